// Round 4
// baseline (265.402 us; speedup 1.0000x reference)
//
#include <hip/hip_runtime.h>

#define C_CH 173
#define L_IN 400
#define EPSV 1e-5f
#define KFEAT 55360  // C*32*10

typedef __fp16   fp16x2 __attribute__((ext_vector_type(2)));
typedef _Float16 f16x8  __attribute__((ext_vector_type(8)));
typedef float    f32x4  __attribute__((ext_vector_type(4)));
typedef float    f32x16 __attribute__((ext_vector_type(16)));

// y1T row: 16 g-values (8 dwords) + 1 pad dword. Odd dword stride (9) ->
// conv2 reads and conv1 writes are <=2-way (free). Access via b32s.
#define Y1T_STRIDE_I 9
#define Y1T_ROWS   406  // row r = y1 time t+3; rows 0..2, 403..405 zeroed halo

// segmax: [f][sub], sub = 0..99. Stride 102 f16 = 51 dwords (odd, >=100).
#define SEG_STRIDE 102

// xa padded to 448 f16 (224 dwords, ==0 mod 32) so xb (at +448) aliases the
// SAME bank for the even/odd lane pairs of conv1 -> uniform 2-way (free).
// R3 had xb at +216 dwords (==24 mod 32) -> shifted bank overlap, ~3-way.
#define XA_PAD 448

#define N1 (173 * 3584)  // w2T elems
#define N2 (173 * 512)   // w1T elems
#define N3 (173 * 96)    // BN consts per c
#define NH 8192          // h accumulator (zeroed in prep; fc1 atomicAdds)

// ---------------------------------------------------------------------------
// Prep kernel: per-channel weight layouts + BN consts + zero the h accum.
//  w2T_g[c][dt*512 + f*16 + g] f16 ; w1T_g[c][g*32+k] f16 (k>=9 zero)
//  sc_g[c*96 + r]: r<16 scale1 | r<32 shift1 | r<64 scale2 | r<96 shift2
// ---------------------------------------------------------------------------
__global__ __launch_bounds__(256) void prep_kernel(
    const float* __restrict__ w1, const float* __restrict__ b1,
    const float* __restrict__ g1, const float* __restrict__ beta1,
    const float* __restrict__ m1, const float* __restrict__ v1,
    const float* __restrict__ w2, const float* __restrict__ b2,
    const float* __restrict__ g2, const float* __restrict__ beta2,
    const float* __restrict__ m2, const float* __restrict__ v2,
    _Float16* __restrict__ w2T_g, _Float16* __restrict__ w1T_g,
    float* __restrict__ sc_g, float* __restrict__ h_ws)
{
    const int idx = blockIdx.x * 256 + threadIdx.x;
    if (idx < N1) {
        int c = idx / 3584, r = idx - c * 3584;
        int dt = r >> 9, fg = r & 511;
        int f = fg >> 4, g = fg & 15;
        w2T_g[idx] = (_Float16)w2[c * 3584 + f * 112 + g * 7 + dt];
    } else if (idx < N1 + N2) {
        int j = idx - N1;
        int c = j / 512, r = j - c * 512;
        int g = r >> 5, k = r & 31;
        w1T_g[j] = (k < 9) ? (_Float16)w1[c * 144 + g * 9 + k] : (_Float16)0.0f;
    } else if (idx < N1 + N2 + N3) {
        int j = idx - N1 - N2;
        int c = j / 96, r = j - c * 96;
        float o;
        if (r < 32) {
            int g  = r & 15;
            int cf = c * 16 + g;
            float inv = g1[cf] * rsqrtf(v1[cf] + EPSV);
            o = (r < 16) ? inv : (b1[cf] - m1[cf]) * inv + beta1[cf];
        } else {
            int f  = (r - 32) & 31;
            int cf = c * 32 + f;
            float inv = g2[cf] * rsqrtf(v2[cf] + EPSV);
            o = (r < 64) ? inv : (b2[cf] - m2[cf]) * inv + beta2[cf];
        }
        sc_g[j] = o;
    } else if (idx < N1 + N2 + N3 + NH) {
        h_ws[idx - N1 - N2 - N3] = 0.0f;
    }
}

// ---------------------------------------------------------------------------
// Tower kernel: one block per (c, batch-group of 4). 320 threads = 5 waves.
// R4: w2T_s/w1T_s LDS staging REMOVED — af/a1 fragments read straight from
// global (w2T_g/w1T_g, L1-resident: 3.5KB/channel shared by all 5 waves).
// Kills the 4-way-conflicted stride-8 ds_read_b128 class (R3's hoist failed:
// compiler rematerialized from LDS, VGPR=36) and the staging loop.
// xa/xb merged with XA_PAD=448 -> conv1 x reads uniform 2-way (free).
// LDS 23.3 KB -> 6 blocks/CU (30 waves/CU).
// ---------------------------------------------------------------------------
__global__ __launch_bounds__(320, 8) void tower_kernel(
    const float* __restrict__ x,
    const _Float16* __restrict__ w2T_g, const _Float16* __restrict__ w1T_g,
    const float* __restrict__ sc_g,
    _Float16* __restrict__ featH)
{
    __shared__ __align__(16) _Float16 xs_s[XA_PAD + 432];    // xa | xb
    __shared__ __align__(16) _Float16 y1T_s[Y1T_ROWS * 2 * Y1T_STRIDE_I];
    __shared__ _Float16               segmax_s[32 * SEG_STRIDE]; // [f][sub]
    __shared__ __align__(16) float    cst_s[96];  // s1[16] sh1[16] s2[32] sh2[32]

    const int c   = blockIdx.x;
    const int tid = threadIdx.x;

    // ---- once-per-block staging: BN consts + y1T halo zero ----
    {
        const float4* csrc = (const float4*)(sc_g + c * 96);
        if (tid < 24) ((float4*)cst_s)[tid] = csrc[tid];
        if (tid >= 64 && tid < 118) {       // 6 rows x 9 dwords
            int i = tid - 64;
            int r = i / 9, cx = i - r * 9;
            int row = (r < 3) ? r : (400 + r);
            ((int*)y1T_s)[row * Y1T_STRIDE_I + cx] = 0;
        }
    }
    __syncthreads();

    // ---- per-lane constants & hoisted fragments (c-only, batch-invariant) ----
    const int lane  = tid & 63;
    const int wv    = tid >> 6;
    const int nlane = lane & 31;
    const int half  = lane >> 5;
    const float s2f  = cst_s[32 + nlane];
    const float sh2f = cst_s[64 + nlane];

    const int nl = lane & 15;         // conv1 m-lane
    const int q1 = lane >> 4;         // conv1 k-group
    union { int4 v; f16x8 h; } a1;
    a1.v = ((const int4*)(w1T_g + (size_t)c * 512))[nl * 4 + q1];
    float s1r[4], sh1r[4];
#pragma unroll
    for (int r = 0; r < 4; ++r) {
        s1r[r]  = cst_s[q1 * 4 + r];
        sh1r[r] = cst_s[16 + q1 * 4 + r];
    }
    // conv2 w2 fragments: read per-tile from global (L1 hit) — no LDS, no
    // register-liveness battle. Pointer hoisted here.
    const int4* w2p = (const int4*)(w2T_g + (size_t)c * 3584);

    for (int nb = 0; nb < 4; ++nb) {
        const int b = blockIdx.y * 4 + nb;

        // ---- stage x as f16 parity copies (xa | xb at +XA_PAD) ----
        const float* xrow = x + ((size_t)b * C_CH + c) * L_IN;
        for (int i = tid; i < 432; i += 320) {
            float v = (i >= 4 && i < 404) ? xrow[i - 4] : 0.0f;
            _Float16 h = (_Float16)v;
            xs_s[i] = h;
            if (i > 0) xs_s[XA_PAD + i - 1] = h;
        }
        if (tid == 0) xs_s[XA_PAD + 431] = (_Float16)0.0f;
        __syncthreads();

        // ---- conv1 via mfma_16x16x32_f16 -> y1T ----
        // A[m=g][k]=w1T; B[k][n]=x_s[t0+n+k-4] (+4 shift folded into x_s).
        {
            const int* xsel = (const int*)((nl & 1) ? (xs_s + XA_PAD) : xs_s);
            for (int tile = 0; tile < 5; ++tile) {
                const int t0 = (wv * 5 + tile) * 16;
                const int dw = (t0 + nl + q1 * 8) >> 1;
                union { int4 v; f16x8 h; } bf;
                bf.v.x = xsel[dw];
                bf.v.y = xsel[dw + 1];
                bf.v.z = xsel[dw + 2];
                bf.v.w = xsel[dw + 3];
                f32x4 acc = {0.0f, 0.0f, 0.0f, 0.0f};
                acc = __builtin_amdgcn_mfma_f32_16x16x32_f16(a1.h, bf.h, acc, 0, 0, 0);
                union { _Float16 h[4]; int2 d; } pk;
#pragma unroll
                for (int r = 0; r < 4; ++r) {
                    float v = acc[r] * s1r[r] + sh1r[r];
                    pk.h[r] = (_Float16)(v > 0.0f ? v : 0.0f);
                }
                int* yp = (int*)y1T_s + (t0 + nl + 3) * Y1T_STRIDE_I + q1 * 2;
                yp[0] = pk.d.x;
                yp[1] = pk.d.y;
            }
        }
        __syncthreads();

        // ---- conv2 MFMA (A=y1 time rows, B=w2) + per-lane subseg max ----
        // acc = D[t][f]: f = nlane, t = tile*32 + (reg&3)+8*(reg>>2)+4*half.
        {
            for (int tile = wv; tile < 13; tile += 5) {
                const int tA  = tile * 32 + nlane;
                const int tAr = tA < 400 ? tA : 399;   // clamp; bad rows discarded
                f32x16 acc;
#pragma unroll
                for (int i = 0; i < 16; ++i) acc[i] = 0.0f;

#pragma unroll
                for (int dt = 0; dt < 7; ++dt) {
                    union { int4 q; f16x8 h; } af;
                    af.q = w2p[dt * 64 + nlane * 2 + half];   // L1 hit
                    const int* p = (const int*)y1T_s + (tAr + dt) * Y1T_STRIDE_I + half * 4;
                    union { int d[4]; f16x8 h; } bf;
                    bf.d[0] = p[0];
                    bf.d[1] = p[1];
                    bf.d[2] = p[2];
                    bf.d[3] = p[3];
                    acc = __builtin_amdgcn_mfma_f32_32x32x16_f16(bf.h, af.h, acc, 0, 0, 0);
                }

                const int base = nlane * SEG_STRIDE + tile * 8 + half;
#pragma unroll
                for (int q = 0; q < 4; ++q) {
                    // scale per element (sign-safe wrt g2), defer shift+relu
                    float v0 = acc[4 * q + 0] * s2f;
                    float v1 = acc[4 * q + 1] * s2f;
                    float v2 = acc[4 * q + 2] * s2f;
                    float v3 = acc[4 * q + 3] * s2f;
                    float m  = fmaxf(fmaxf(v0, v1), fmaxf(v2, v3));
                    const int sub = tile * 8 + 2 * q + half;
                    if (sub < 100) segmax_s[base + 2 * q] = (_Float16)m;
                }
            }
        }
        __syncthreads();

        // ---- pool(40) = max of 10 subseg-maxes; apply shift + relu ----
        {
            const int f = tid & 31;
            const int p = tid >> 5;
            float m = -3.0e38f;
#pragma unroll
            for (int k = 0; k < 10; ++k)
                m = fmaxf(m, (float)segmax_s[f * SEG_STRIDE + p * 10 + k]);
            float v = fmaxf(m + sh2f, 0.0f);
            featH[(size_t)b * KFEAT + (c * 32 + f) * 10 + p] = (_Float16)v;
        }
        // barrier audit: next x-stage writes xs only, whose last readers
        // (conv1) are fenced by two syncs; segmax(i) fully consumed before
        // any wave passes the next post-stage sync; y1T rewritten only after
        // the post-stage sync. Same structure as R2/R3 (verified passing).
    }
}

// ---------------------------------------------------------------------------
// FC1: 173 blocks x 512 threads (8 waves = 2/SIMD, was 1/SIMD).
// Wave w: k-half kh=w>>2 (160 k, 10 steps — half the serial chain), j-quarter
// jq=w&3. kh=1 tiles combined via LDS, then fp32 atomicAdd into h
// (prep zeroes h; stream order prep->tower->fc1 makes this graph-safe).
// Eliminates the 11.4 MB part round-trip + the reduce kernel.
// ---------------------------------------------------------------------------
__global__ __launch_bounds__(512) void fc1_kernel(
    const _Float16* __restrict__ featH, const float* __restrict__ wc1,
    float* __restrict__ h_ws)
{
    __shared__ float red[4 * 2048];

    const int tid   = threadIdx.x;
    const int w     = tid >> 6;
    const int lane  = tid & 63;
    const int nlane = lane & 31;
    const int half  = lane >> 5;
    const int kh    = w >> 2;
    const int jq    = w & 3;
    const int jrow  = jq * 32 + nlane;
    const int k0    = blockIdx.x * 320 + kh * 160;

    const float*    ap  = wc1   + (size_t)jrow * KFEAT + k0 + half * 8;
    const _Float16* b0p = featH + (size_t)nlane * KFEAT + k0 + half * 8;
    const _Float16* b1p = featH + (size_t)(nlane + 32) * KFEAT + k0 + half * 8;

    f32x16 acc0, acc1;
#pragma unroll
    for (int i = 0; i < 16; ++i) { acc0[i] = 0.0f; acc1[i] = 0.0f; }

#pragma unroll 5
    for (int s = 0; s < 10; ++s) {
        const float4 aw0 = *(const float4*)(ap + s * 16);
        const float4 aw1 = *(const float4*)(ap + s * 16 + 4);
        union { fp16x2 v2[4]; f16x8 h; } a;
        a.v2[0] = __builtin_amdgcn_cvt_pkrtz(aw0.x, aw0.y);
        a.v2[1] = __builtin_amdgcn_cvt_pkrtz(aw0.z, aw0.w);
        a.v2[2] = __builtin_amdgcn_cvt_pkrtz(aw1.x, aw1.y);
        a.v2[3] = __builtin_amdgcn_cvt_pkrtz(aw1.z, aw1.w);

        union { int4 q; f16x8 h; } b0, b1;
        b0.q = *(const int4*)(b0p + s * 16);
        b1.q = *(const int4*)(b1p + s * 16);

        acc0 = __builtin_amdgcn_mfma_f32_32x32x16_f16(a.h, b0.h, acc0, 0, 0, 0);
        acc1 = __builtin_amdgcn_mfma_f32_32x32x16_f16(a.h, b1.h, acc1, 0, 0, 0);
    }

    if (kh == 1) {
        float* rp = red + jq * 2048;
#pragma unroll
        for (int reg = 0; reg < 16; ++reg) {
            rp[(reg * 2 + half) * 64 + nlane]      = acc0[reg];
            rp[(reg * 2 + half) * 64 + 32 + nlane] = acc1[reg];
        }
    }
    __syncthreads();
    if (kh == 0) {
        const float* rp = red + jq * 2048;
#pragma unroll
        for (int reg = 0; reg < 16; ++reg) {
            int j = jq * 32 + (reg & 3) + 8 * (reg >> 2) + 4 * half;
            float v0 = acc0[reg] + rp[(reg * 2 + half) * 64 + nlane];
            float v1 = acc1[reg] + rp[(reg * 2 + half) * 64 + 32 + nlane];
            atomicAdd(&h_ws[j * 64 + nlane], v0);
            atomicAdd(&h_ws[j * 64 + 32 + nlane], v1);
        }
    }
}

// ---------------------------------------------------------------------------
// FC2: one block, 512 threads. b = t&63 (coalesced h reads), j chunked 8-way.
// ---------------------------------------------------------------------------
__global__ __launch_bounds__(512) void fc2_kernel(
    const float* __restrict__ h_ws, const float* __restrict__ bc1,
    const float* __restrict__ wc2, const float* __restrict__ bc2,
    float* __restrict__ out)
{
    __shared__ float partial[512];
    const int t  = threadIdx.x;
    const int b  = t & 63;
    const int jc = t >> 6;
    float s = 0.0f;
#pragma unroll
    for (int jj = 0; jj < 16; ++jj) {
        const int j = jc * 16 + jj;
        float hv = h_ws[j * 64 + b] + bc1[j];
        hv = hv > 0.0f ? hv : 0.0f;
        s += wc2[j] * hv;
    }
    partial[t] = s;
    __syncthreads();
    if (t < 64) {
        float r = partial[t];
#pragma unroll
        for (int k = 1; k < 8; ++k) r += partial[t + 64 * k];
        out[b] = r + bc2[0];
    }
}

extern "C" void kernel_launch(void* const* d_in, const int* in_sizes, int n_in,
                              void* d_out, int out_size, void* d_ws, size_t ws_size,
                              hipStream_t stream)
{
    const float* x     = (const float*)d_in[0];
    const float* w1    = (const float*)d_in[1];
    const float* b1    = (const float*)d_in[2];
    const float* g1    = (const float*)d_in[3];
    const float* beta1 = (const float*)d_in[4];
    const float* m1    = (const float*)d_in[5];
    const float* v1    = (const float*)d_in[6];
    const float* w2    = (const float*)d_in[7];
    const float* b2    = (const float*)d_in[8];
    const float* g2    = (const float*)d_in[9];
    const float* beta2 = (const float*)d_in[10];
    const float* m2    = (const float*)d_in[11];
    const float* v2    = (const float*)d_in[12];
    const float* wc1   = (const float*)d_in[13];
    const float* bc1   = (const float*)d_in[14];
    const float* wc2   = (const float*)d_in[15];
    const float* bc2   = (const float*)d_in[16];

    char* ws = (char*)d_ws;
    _Float16* featH = (_Float16*)ws;                          // 7,086,080 B
    _Float16* w2T_g = (_Float16*)(ws + 7086080);              // 1,240,064 B
    _Float16* w1T_g = (_Float16*)(ws + 8326144);              // 177,152 B
    float*    sc_g  = (float*)(ws + 8503296);                 // 66,432 B
    float*    h_ws  = (float*)(ws + 8569728);                 // 32,768 B

    // (N1+N2+N3+NH) = 733,408 -> 2865 blocks of 256
    hipLaunchKernelGGL(prep_kernel, dim3(2865), dim3(256), 0, stream,
                       w1, b1, g1, beta1, m1, v1,
                       w2, b2, g2, beta2, m2, v2, w2T_g, w1T_g, sc_g, h_ws);

    hipLaunchKernelGGL(tower_kernel, dim3(C_CH, 16), dim3(320), 0, stream,
                       x, w2T_g, w1T_g, sc_g, featH);

    hipLaunchKernelGGL(fc1_kernel, dim3(173), dim3(512), 0, stream,
                       featH, wc1, h_ws);

    hipLaunchKernelGGL(fc2_kernel, dim3(1), dim3(512), 0, stream,
                       h_ws, bc1, wc2, bc2, (float*)d_out);
}

// Round 5
// 258.635 us; speedup vs baseline: 1.0262x; 1.0262x over previous
//
#include <hip/hip_runtime.h>

#define C_CH 173
#define L_IN 400
#define EPSV 1e-5f
#define KFEAT 55360  // C*32*10

typedef __fp16   fp16x2 __attribute__((ext_vector_type(2)));
typedef _Float16 f16x8  __attribute__((ext_vector_type(8)));
typedef float    f32x4  __attribute__((ext_vector_type(4)));
typedef float    f32x16 __attribute__((ext_vector_type(16)));

// y1T row: 16 f16 = 8 dwords, NO pad (R5). Rows 16B-aligned ->
//  conv2 fragment read = 1x ds_read_b128 (start banks (8t+4h)%32: uniform
//  8 granules/bank = floor), conv1 store = 1x ds_write_b64 (uniform 4/bank).
// This replaces R2-R4's stride-9 rows (4x b32 per fragment, 28 b32/tile).
#define Y1T_ROWS 406  // row r = y1 time t+3; rows 0..2, 403..405 zeroed halo

// segmax R5: halves pair-combined via shfl_xor(32) before store ->
// [f][pair 0..49] of 8-time maxes; pool window p = pairs 5p..5p+4.
// Stride 52 f16 = 26 dwords (gcd 2 with 32 -> 2-way = free).
#define SEG_STRIDE 52

// xa padded to 448 f16 (224 dwords, ==0 mod 32) so xb (at +448) aliases the
// SAME bank for the even/odd lane pairs of conv1 -> uniform 2-way (free).
#define XA_PAD 448

#define N1 (173 * 3584)  // w2T elems
#define N2 (173 * 512)   // w1T elems
#define N3 (173 * 96)    // BN consts per c
#define NH 8192          // h accumulator (zeroed in prep; fc1 atomicAdds)

// ---------------------------------------------------------------------------
// Prep kernel: per-channel weight layouts + BN consts + zero the h accum.
//  w2T_g[c][dt*512 + f*16 + g] f16 ; w1T_g[c][g*32+k] f16 (k>=9 zero)
//  sc_g[c*96 + r]: r<16 scale1 | r<32 shift1 | r<64 scale2 | r<96 shift2
// ---------------------------------------------------------------------------
__global__ __launch_bounds__(256) void prep_kernel(
    const float* __restrict__ w1, const float* __restrict__ b1,
    const float* __restrict__ g1, const float* __restrict__ beta1,
    const float* __restrict__ m1, const float* __restrict__ v1,
    const float* __restrict__ w2, const float* __restrict__ b2,
    const float* __restrict__ g2, const float* __restrict__ beta2,
    const float* __restrict__ m2, const float* __restrict__ v2,
    _Float16* __restrict__ w2T_g, _Float16* __restrict__ w1T_g,
    float* __restrict__ sc_g, float* __restrict__ h_ws)
{
    const int idx = blockIdx.x * 256 + threadIdx.x;
    if (idx < N1) {
        int c = idx / 3584, r = idx - c * 3584;
        int dt = r >> 9, fg = r & 511;
        int f = fg >> 4, g = fg & 15;
        w2T_g[idx] = (_Float16)w2[c * 3584 + f * 112 + g * 7 + dt];
    } else if (idx < N1 + N2) {
        int j = idx - N1;
        int c = j / 512, r = j - c * 512;
        int g = r >> 5, k = r & 31;
        w1T_g[j] = (k < 9) ? (_Float16)w1[c * 144 + g * 9 + k] : (_Float16)0.0f;
    } else if (idx < N1 + N2 + N3) {
        int j = idx - N1 - N2;
        int c = j / 96, r = j - c * 96;
        float o;
        if (r < 32) {
            int g  = r & 15;
            int cf = c * 16 + g;
            float inv = g1[cf] * rsqrtf(v1[cf] + EPSV);
            o = (r < 16) ? inv : (b1[cf] - m1[cf]) * inv + beta1[cf];
        } else {
            int f  = (r - 32) & 31;
            int cf = c * 32 + f;
            float inv = g2[cf] * rsqrtf(v2[cf] + EPSV);
            o = (r < 64) ? inv : (b2[cf] - m2[cf]) * inv + beta2[cf];
        }
        sc_g[j] = o;
    } else if (idx < N1 + N2 + N3 + NH) {
        h_ws[idx - N1 - N2 - N3] = 0.0f;
    }
}

// ---------------------------------------------------------------------------
// Tower kernel: one block per (c, batch-group of 4). 320 threads = 5 waves.
// R5: REVERT R4's per-tile global w2 reads (caused 240MB L2-fetch storm,
// MfmaUtil 10%) -> w2T staged in LDS once per block; af[7] hoisted per batch
// (liveness doesn't cross a barrier -> compiler can hold 28 VGPRs).
// y1T stride 8 dwords: b128 reads / b64 writes at uniform bank coverage.
// segmax pair-combined via shfl_xor(32): LDS 25.6KB -> 6 blocks/CU.
// w1T/a1 + sc still read from global once per block (tiny, not repeated).
// ---------------------------------------------------------------------------
__global__ __launch_bounds__(320, 8) void tower_kernel(
    const float* __restrict__ x,
    const _Float16* __restrict__ w2T_g, const _Float16* __restrict__ w1T_g,
    const float* __restrict__ sc_g,
    _Float16* __restrict__ featH)
{
    __shared__ __align__(16) _Float16 xs_s[XA_PAD + 432];    // xa | xb
    __shared__ __align__(16) _Float16 y1T_s[Y1T_ROWS * 16];  // [row][16]
    __shared__ __align__(16) _Float16 w2T_s[7 * 512];        // [dt][f][g]
    __shared__ _Float16               segmax_s[32 * SEG_STRIDE]; // [f][pair]
    __shared__ __align__(16) float    cst_s[96];  // s1[16] sh1[16] s2[32] sh2[32]

    const int c   = blockIdx.x;
    const int tid = threadIdx.x;

    // ---- once-per-block staging ----
    {
        const int4* w2src = (const int4*)(w2T_g + (size_t)c * 3584);
        for (int i = tid; i < 448; i += 320) ((int4*)w2T_s)[i] = w2src[i];
        const float4* csrc = (const float4*)(sc_g + c * 96);
        if (tid < 24) ((float4*)cst_s)[tid] = csrc[tid];
        // zero y1T halo rows 0..2 and 403..405 (6 rows x 8 dwords)
        if (tid >= 64 && tid < 112) {
            int i = tid - 64;
            int r = i >> 3, cx = i & 7;
            int row = (r < 3) ? r : (400 + r);
            ((int*)y1T_s)[row * 8 + cx] = 0;
        }
    }
    __syncthreads();

    // ---- per-lane constants & batch-invariant fragments ----
    const int lane  = tid & 63;
    const int wv    = tid >> 6;
    const int nlane = lane & 31;
    const int half  = lane >> 5;
    const float s2f  = cst_s[32 + nlane];
    const float sh2f = cst_s[64 + nlane];

    const int nl = lane & 15;         // conv1 m-lane
    const int q1 = lane >> 4;         // conv1 k-group
    union { int4 v; f16x8 h; } a1;
    a1.v = ((const int4*)(w1T_g + (size_t)c * 512))[nl * 4 + q1];
    float s1r[4], sh1r[4];
#pragma unroll
    for (int r = 0; r < 4; ++r) {
        s1r[r]  = cst_s[q1 * 4 + r];
        sh1r[r] = cst_s[16 + q1 * 4 + r];
    }

    for (int nb = 0; nb < 4; ++nb) {
        const int b = blockIdx.y * 4 + nb;

        // ---- stage x as f16 parity copies (xa | xb at +XA_PAD) ----
        const float* xrow = x + ((size_t)b * C_CH + c) * L_IN;
        for (int i = tid; i < 432; i += 320) {
            float v = (i >= 4 && i < 404) ? xrow[i - 4] : 0.0f;
            _Float16 h = (_Float16)v;
            xs_s[i] = h;
            if (i > 0) xs_s[XA_PAD + i - 1] = h;
        }
        if (tid == 0) xs_s[XA_PAD + 431] = (_Float16)0.0f;
        __syncthreads();

        // ---- conv1 via mfma_16x16x32_f16 -> y1T ----
        // A[m=g][k]=w1T; B[k][n]=x_s[t0+n+k-4] (+4 shift folded into x_s).
        {
            const int* xsel = (const int*)((nl & 1) ? (xs_s + XA_PAD) : xs_s);
            for (int tile = 0; tile < 5; ++tile) {
                const int t0 = (wv * 5 + tile) * 16;
                const int dw = (t0 + nl + q1 * 8) >> 1;
                union { int4 v; f16x8 h; } bf;
                bf.v.x = xsel[dw];
                bf.v.y = xsel[dw + 1];
                bf.v.z = xsel[dw + 2];
                bf.v.w = xsel[dw + 3];
                f32x4 acc = {0.0f, 0.0f, 0.0f, 0.0f};
                acc = __builtin_amdgcn_mfma_f32_16x16x32_f16(a1.h, bf.h, acc, 0, 0, 0);
                union { _Float16 h[4]; int2 d; } pk;
#pragma unroll
                for (int r = 0; r < 4; ++r) {
                    float v = acc[r] * s1r[r] + sh1r[r];
                    pk.h[r] = (_Float16)(v > 0.0f ? v : 0.0f);
                }
                // row stride 8 dwords, 8B-aligned -> single ds_write_b64
                *(int2*)((int*)y1T_s + (t0 + nl + 3) * 8 + q1 * 2) = pk.d;
            }
        }
        __syncthreads();

        // ---- conv2 MFMA (A=y1 time rows, B=w2 from LDS) + pair max ----
        // acc = D[t][f]: f = nlane, t = tile*32 + (reg&3)+8*(reg>>2)+4*half.
        // Reg quad q covers t = tile*32 + 8q + 4*half + {0..3} -> one 4-time
        // subseg; shfl_xor(32) pairs the two halves -> 8-time pair max.
        {
            union F8q { int4 q; f16x8 h; } af[7];
#pragma unroll
            for (int dt = 0; dt < 7; ++dt)
                af[dt].q = *(const int4*)((const int*)w2T_s + dt * 256 + nlane * 8 + half * 4);

            for (int tile = wv; tile < 13; tile += 5) {
                const int tA  = tile * 32 + nlane;
                const int tAr = tA < 400 ? tA : 399;   // clamp; bad rows -> pair>=50, discarded
                f32x16 acc;
#pragma unroll
                for (int i = 0; i < 16; ++i) acc[i] = 0.0f;

#pragma unroll
                for (int dt = 0; dt < 7; ++dt) {
                    union { int4 q; f16x8 h; } bf;
                    // 16B-aligned single ds_read_b128
                    bf.q = *(const int4*)((const int*)y1T_s + (tAr + dt) * 8 + half * 4);
                    acc = __builtin_amdgcn_mfma_f32_32x32x16_f16(bf.h, af[dt].h, acc, 0, 0, 0);
                }

#pragma unroll
                for (int q = 0; q < 4; ++q) {
                    // scale per element (sign-safe wrt g2), defer shift+relu
                    float v0 = acc[4 * q + 0] * s2f;
                    float v1 = acc[4 * q + 1] * s2f;
                    float v2 = acc[4 * q + 2] * s2f;
                    float v3 = acc[4 * q + 3] * s2f;
                    float m  = fmaxf(fmaxf(v0, v1), fmaxf(v2, v3));
                    float pm = fmaxf(m, __shfl_xor(m, 32));
                    const int pair = tile * 4 + q;
                    if (half == 0 && pair < 50)
                        segmax_s[nlane * SEG_STRIDE + pair] = (_Float16)pm;
                }
            }
        }
        __syncthreads();

        // ---- pool(40) = max of 5 pair-maxes; apply shift + relu ----
        {
            const int f = tid & 31;
            const int p = tid >> 5;
            float m = -3.0e38f;
#pragma unroll
            for (int k = 0; k < 5; ++k)
                m = fmaxf(m, (float)segmax_s[f * SEG_STRIDE + p * 5 + k]);
            float v = fmaxf(m + sh2f, 0.0f);
            featH[(size_t)b * KFEAT + (c * 32 + f) * 10 + p] = (_Float16)v;
        }
        // barrier audit: next x-stage writes xs only (its last readers are
        // fenced by two syncs); segmax(i) fully consumed before any wave
        // passes the next post-stage sync; y1T rewritten only after the
        // post-stage sync. Structure identical to R2/R3 (verified passing).
    }
}

// ---------------------------------------------------------------------------
// FC1: 173 blocks x 512 threads (8 waves = 2/SIMD).
// Wave w: k-half kh=w>>2 (160 k, 10 steps), j-quarter jq=w&3. kh=1 tiles
// combined via LDS, then fp32 atomicAdd into h (prep zeroes h).
// ---------------------------------------------------------------------------
__global__ __launch_bounds__(512) void fc1_kernel(
    const _Float16* __restrict__ featH, const float* __restrict__ wc1,
    float* __restrict__ h_ws)
{
    __shared__ float red[4 * 2048];

    const int tid   = threadIdx.x;
    const int w     = tid >> 6;
    const int lane  = tid & 63;
    const int nlane = lane & 31;
    const int half  = lane >> 5;
    const int kh    = w >> 2;
    const int jq    = w & 3;
    const int jrow  = jq * 32 + nlane;
    const int k0    = blockIdx.x * 320 + kh * 160;

    const float*    ap  = wc1   + (size_t)jrow * KFEAT + k0 + half * 8;
    const _Float16* b0p = featH + (size_t)nlane * KFEAT + k0 + half * 8;
    const _Float16* b1p = featH + (size_t)(nlane + 32) * KFEAT + k0 + half * 8;

    f32x16 acc0, acc1;
#pragma unroll
    for (int i = 0; i < 16; ++i) { acc0[i] = 0.0f; acc1[i] = 0.0f; }

#pragma unroll 5
    for (int s = 0; s < 10; ++s) {
        const float4 aw0 = *(const float4*)(ap + s * 16);
        const float4 aw1 = *(const float4*)(ap + s * 16 + 4);
        union { fp16x2 v2[4]; f16x8 h; } a;
        a.v2[0] = __builtin_amdgcn_cvt_pkrtz(aw0.x, aw0.y);
        a.v2[1] = __builtin_amdgcn_cvt_pkrtz(aw0.z, aw0.w);
        a.v2[2] = __builtin_amdgcn_cvt_pkrtz(aw1.x, aw1.y);
        a.v2[3] = __builtin_amdgcn_cvt_pkrtz(aw1.z, aw1.w);

        union { int4 q; f16x8 h; } b0, b1;
        b0.q = *(const int4*)(b0p + s * 16);
        b1.q = *(const int4*)(b1p + s * 16);

        acc0 = __builtin_amdgcn_mfma_f32_32x32x16_f16(a.h, b0.h, acc0, 0, 0, 0);
        acc1 = __builtin_amdgcn_mfma_f32_32x32x16_f16(a.h, b1.h, acc1, 0, 0, 0);
    }

    if (kh == 1) {
        float* rp = red + jq * 2048;
#pragma unroll
        for (int reg = 0; reg < 16; ++reg) {
            rp[(reg * 2 + half) * 64 + nlane]      = acc0[reg];
            rp[(reg * 2 + half) * 64 + 32 + nlane] = acc1[reg];
        }
    }
    __syncthreads();
    if (kh == 0) {
        const float* rp = red + jq * 2048;
#pragma unroll
        for (int reg = 0; reg < 16; ++reg) {
            int j = jq * 32 + (reg & 3) + 8 * (reg >> 2) + 4 * half;
            float v0 = acc0[reg] + rp[(reg * 2 + half) * 64 + nlane];
            float v1 = acc1[reg] + rp[(reg * 2 + half) * 64 + 32 + nlane];
            atomicAdd(&h_ws[j * 64 + nlane], v0);
            atomicAdd(&h_ws[j * 64 + 32 + nlane], v1);
        }
    }
}

// ---------------------------------------------------------------------------
// FC2: one block, 512 threads. b = t&63 (coalesced h reads), j chunked 8-way.
// ---------------------------------------------------------------------------
__global__ __launch_bounds__(512) void fc2_kernel(
    const float* __restrict__ h_ws, const float* __restrict__ bc1,
    const float* __restrict__ wc2, const float* __restrict__ bc2,
    float* __restrict__ out)
{
    __shared__ float partial[512];
    const int t  = threadIdx.x;
    const int b  = t & 63;
    const int jc = t >> 6;
    float s = 0.0f;
#pragma unroll
    for (int jj = 0; jj < 16; ++jj) {
        const int j = jc * 16 + jj;
        float hv = h_ws[j * 64 + b] + bc1[j];
        hv = hv > 0.0f ? hv : 0.0f;
        s += wc2[j] * hv;
    }
    partial[t] = s;
    __syncthreads();
    if (t < 64) {
        float r = partial[t];
#pragma unroll
        for (int k = 1; k < 8; ++k) r += partial[t + 64 * k];
        out[b] = r + bc2[0];
    }
}

extern "C" void kernel_launch(void* const* d_in, const int* in_sizes, int n_in,
                              void* d_out, int out_size, void* d_ws, size_t ws_size,
                              hipStream_t stream)
{
    const float* x     = (const float*)d_in[0];
    const float* w1    = (const float*)d_in[1];
    const float* b1    = (const float*)d_in[2];
    const float* g1    = (const float*)d_in[3];
    const float* beta1 = (const float*)d_in[4];
    const float* m1    = (const float*)d_in[5];
    const float* v1    = (const float*)d_in[6];
    const float* w2    = (const float*)d_in[7];
    const float* b2    = (const float*)d_in[8];
    const float* g2    = (const float*)d_in[9];
    const float* beta2 = (const float*)d_in[10];
    const float* m2    = (const float*)d_in[11];
    const float* v2    = (const float*)d_in[12];
    const float* wc1   = (const float*)d_in[13];
    const float* bc1   = (const float*)d_in[14];
    const float* wc2   = (const float*)d_in[15];
    const float* bc2   = (const float*)d_in[16];

    char* ws = (char*)d_ws;
    _Float16* featH = (_Float16*)ws;                          // 7,086,080 B
    _Float16* w2T_g = (_Float16*)(ws + 7086080);              // 1,240,064 B
    _Float16* w1T_g = (_Float16*)(ws + 8326144);              // 177,152 B
    float*    sc_g  = (float*)(ws + 8503296);                 // 66,432 B
    float*    h_ws  = (float*)(ws + 8569728);                 // 32,768 B

    // (N1+N2+N3+NH) = 733,408 -> 2865 blocks of 256
    hipLaunchKernelGGL(prep_kernel, dim3(2865), dim3(256), 0, stream,
                       w1, b1, g1, beta1, m1, v1,
                       w2, b2, g2, beta2, m2, v2, w2T_g, w1T_g, sc_g, h_ws);

    hipLaunchKernelGGL(tower_kernel, dim3(C_CH, 16), dim3(320), 0, stream,
                       x, w2T_g, w1T_g, sc_g, featH);

    hipLaunchKernelGGL(fc1_kernel, dim3(173), dim3(512), 0, stream,
                       featH, wc1, h_ws);

    hipLaunchKernelGGL(fc2_kernel, dim3(1), dim3(512), 0, stream,
                       h_ws, bc1, wc2, bc2, (float*)d_out);
}

// Round 6
// 208.334 us; speedup vs baseline: 1.2739x; 1.2414x over previous
//
#include <hip/hip_runtime.h>

#define C_CH 173
#define L_IN 400
#define EPSV 1e-5f
#define KFEAT 55360  // C*32*10

typedef __fp16   fp16x2 __attribute__((ext_vector_type(2)));
typedef _Float16 f16x8  __attribute__((ext_vector_type(8)));
typedef float    f32x4  __attribute__((ext_vector_type(4)));
typedef float    f32x16 __attribute__((ext_vector_type(16)));

// y1T row: 16 f16 + 1 pad dword = 9 dwords (R2-proven). Odd dword stride ->
// conv2 4xb32 reads and conv1 b32-pair writes are conflict-free
// (banks 9*row%32 are a permutation, gcd(9,32)=1).
#define Y1T_STRIDE_I 9
#define Y1T_ROWS   406  // row r = y1 time t+3; rows 0..2, 403..405 zeroed halo

// segmax: halves pair-combined via shfl_xor(32) -> [f][pair 0..49] of 8-time
// maxes; pool p = pairs 5p..5p+4. Stride 50 f16 = 25 dwords (gcd(25,32)=1).
#define SEG_STRIDE 50

// xa padded to 448 f16 so xb (at +448, ==0 mod 32 dwords) gives the conv1
// even/odd lane pairs the SAME bank pattern -> uniform 2-way (free).
#define XA_PAD 448

#define N1 (173 * 3584)  // w2T elems
#define N2 (173 * 512)   // w1T elems
#define N3 (173 * 96)    // BN consts per c
#define NH 8192          // h accumulator (zeroed in prep; fc1 atomicAdds)

// ---------------------------------------------------------------------------
// Prep kernel: per-channel weight layouts + BN consts + zero the h accum.
//  w2T_g[c][dt*512 + f*16 + g] f16 (linear; swizzle applied at LDS staging)
//  w1T_g[c][g*32+k] f16 (k>=9 zero)
//  sc_g[c*96 + r]: r<16 scale1 | r<32 shift1 | r<64 scale2 | r<96 shift2
// ---------------------------------------------------------------------------
__global__ __launch_bounds__(256) void prep_kernel(
    const float* __restrict__ w1, const float* __restrict__ b1,
    const float* __restrict__ g1, const float* __restrict__ beta1,
    const float* __restrict__ m1, const float* __restrict__ v1,
    const float* __restrict__ w2, const float* __restrict__ b2,
    const float* __restrict__ g2, const float* __restrict__ beta2,
    const float* __restrict__ m2, const float* __restrict__ v2,
    _Float16* __restrict__ w2T_g, _Float16* __restrict__ w1T_g,
    float* __restrict__ sc_g, float* __restrict__ h_ws)
{
    const int idx = blockIdx.x * 256 + threadIdx.x;
    if (idx < N1) {
        int c = idx / 3584, r = idx - c * 3584;
        int dt = r >> 9, fg = r & 511;
        int f = fg >> 4, g = fg & 15;
        w2T_g[idx] = (_Float16)w2[c * 3584 + f * 112 + g * 7 + dt];
    } else if (idx < N1 + N2) {
        int j = idx - N1;
        int c = j / 512, r = j - c * 512;
        int g = r >> 5, k = r & 31;
        w1T_g[j] = (k < 9) ? (_Float16)w1[c * 144 + g * 9 + k] : (_Float16)0.0f;
    } else if (idx < N1 + N2 + N3) {
        int j = idx - N1 - N2;
        int c = j / 96, r = j - c * 96;
        float o;
        if (r < 32) {
            int g  = r & 15;
            int cf = c * 16 + g;
            float inv = g1[cf] * rsqrtf(v1[cf] + EPSV);
            o = (r < 16) ? inv : (b1[cf] - m1[cf]) * inv + beta1[cf];
        } else {
            int f  = (r - 32) & 31;
            int cf = c * 32 + f;
            float inv = g2[cf] * rsqrtf(v2[cf] + EPSV);
            o = (r < 64) ? inv : (b2[cf] - m2[cf]) * inv + beta2[cf];
        }
        sc_g[j] = o;
    } else if (idx < N1 + N2 + N3 + NH) {
        h_ws[idx - N1 - N2 - N3] = 0.0f;
    }
}

// ---------------------------------------------------------------------------
// Tower kernel: one block per (c, batch-group of 4). 320 threads = 5 waves.
// R6 = R2-proven structure (stride-9 y1T, full LDS staging, per-batch
// fragment loads, launch_bounds(320,8)) + three deltas:
//  (a) merged xs with XA_PAD (R5-proven),
//  (b) pair-combined segmax via shfl_xor(32) (R5-proven, -3.3KB LDS),
//  (c) XOR-swizzled w2T_s: the af ds_read_b128 at dword 8f+4h starts on
//      banks {0,8,16,24} -> 8-way (this WAS R2's 5.1M conflict source; the
//      same pattern on y1T was R5's 11.6M). Swizzle dword bits [3,4] with
//      (f>>2)&3 on both staging-write and read -> 2-way (free).
// REVERTED from R4/R5: hoisted a1/s1r/sh1r/s2f/sh2f + per-tile global w2 —
// the hoists pushed peak live regs past launch_bounds(320,8)'s 64-VGPR
// budget -> scratch spill -> 186-240MB/dispatch HBM storm (the real R4/R5
// regression). R2's per-batch loads keep peak ~50 regs: VGPR 44, no spill.
// LDS 28.2KB -> 5 blocks/CU.
// ---------------------------------------------------------------------------
__global__ __launch_bounds__(320, 8) void tower_kernel(
    const float* __restrict__ x,
    const _Float16* __restrict__ w2T_g, const _Float16* __restrict__ w1T_g,
    const float* __restrict__ sc_g,
    _Float16* __restrict__ featH)
{
    __shared__ __align__(16) _Float16 xs_s[XA_PAD + 432];        // xa | xb
    __shared__ __align__(16) _Float16 w1T_s[16 * 32];            // [g][k]
    __shared__ __align__(16) _Float16 y1T_s[Y1T_ROWS * 2 * Y1T_STRIDE_I];
    __shared__ __align__(16) _Float16 w2T_s[7 * 512];            // swizzled
    __shared__ _Float16               segmax_s[32 * SEG_STRIDE]; // [f][pair]
    __shared__ __align__(16) float    cst_s[96];  // s1[16] sh1[16] s2[32] sh2[32]

    const int c   = blockIdx.x;
    const int tid = threadIdx.x;

    // ---- once-per-block staging ----
    {
        const int4* w2src = (const int4*)(w2T_g + (size_t)c * 3584);
        // XOR-swizzle int4 index bits [1,2] (byte bits 5,6) with bits [3,4]
        // (= (f>>2)&3). Bijective within each 8-int4 group; dt untouched.
        for (int i = tid; i < 448; i += 320)
            ((int4*)w2T_s)[i ^ (((i >> 3) & 3) << 1)] = w2src[i];
        const int4* w1src = (const int4*)(w1T_g + c * 512);
        if (tid < 64) ((int4*)w1T_s)[tid] = w1src[tid];
        const float4* csrc = (const float4*)(sc_g + c * 96);
        if (tid >= 64 && tid < 88) ((float4*)cst_s)[tid - 64] = csrc[tid - 64];
        // zero y1T halo rows 0..2 and 403..405 (6 rows x 9 dwords)
        if (tid >= 96 && tid < 150) {
            int i = tid - 96;
            int r = i / 9, cx = i - r * 9;
            int row = (r < 3) ? r : (400 + r);
            ((int*)y1T_s)[row * Y1T_STRIDE_I + cx] = 0;
        }
    }
    __syncthreads();

    const int lane  = tid & 63;
    const int wv    = tid >> 6;
    const int nlane = lane & 31;
    const int half  = lane >> 5;
    const int nl    = lane & 15;      // conv1 m-lane
    const int q1    = lane >> 4;      // conv1 k-group

    for (int nb = 0; nb < 4; ++nb) {
        const int b = blockIdx.y * 4 + nb;

        // ---- stage x as f16 parity copies (xa | xb at +XA_PAD) ----
        const float* xrow = x + ((size_t)b * C_CH + c) * L_IN;
        for (int i = tid; i < 432; i += 320) {
            float v = (i >= 4 && i < 404) ? xrow[i - 4] : 0.0f;
            _Float16 h = (_Float16)v;
            xs_s[i] = h;
            if (i > 0) xs_s[XA_PAD + i - 1] = h;
        }
        if (tid == 0) xs_s[XA_PAD + 431] = (_Float16)0.0f;
        __syncthreads();

        // ---- conv1 via mfma_16x16x32_f16 -> y1T ----
        // A[m=g][k]=w1T; B[k][n]=x_s[t0+n+k-4] (+4 shift folded into x_s).
        // Fragments loaded per-batch from LDS (cheap; keeps regs low).
        {
            union { int4 v; f16x8 h; } a1;
            a1.v = *(const int4*)((const int*)w1T_s + nl * 16 + q1 * 4);
            float s1r[4], sh1r[4];
#pragma unroll
            for (int r = 0; r < 4; ++r) {
                s1r[r]  = cst_s[q1 * 4 + r];
                sh1r[r] = cst_s[16 + q1 * 4 + r];
            }
            const int* xsel = (const int*)((nl & 1) ? (xs_s + XA_PAD) : xs_s);
            for (int tile = 0; tile < 5; ++tile) {
                const int t0 = (wv * 5 + tile) * 16;
                const int dw = (t0 + nl + q1 * 8) >> 1;
                union { int4 v; f16x8 h; } bf;
                bf.v.x = xsel[dw];
                bf.v.y = xsel[dw + 1];
                bf.v.z = xsel[dw + 2];
                bf.v.w = xsel[dw + 3];
                f32x4 acc = {0.0f, 0.0f, 0.0f, 0.0f};
                acc = __builtin_amdgcn_mfma_f32_16x16x32_f16(a1.h, bf.h, acc, 0, 0, 0);
                union { _Float16 h[4]; int2 d; } pk;
#pragma unroll
                for (int r = 0; r < 4; ++r) {
                    float v = acc[r] * s1r[r] + sh1r[r];
                    pk.h[r] = (_Float16)(v > 0.0f ? v : 0.0f);
                }
                // stride-9 rows (4B-aligned): two b32 stores, conflict-free
                int* yp = (int*)y1T_s + (t0 + nl + 3) * Y1T_STRIDE_I + q1 * 2;
                yp[0] = pk.d.x;
                yp[1] = pk.d.y;
            }
        }
        __syncthreads();

        // ---- conv2 MFMA (A=y1 time rows, B=w2 swizzled) + pair max ----
        // acc = D[t][f]: f = nlane, t = tile*32 + (reg&3)+8*(reg>>2)+4*half.
        // Reg quad q = 4-time subseg; shfl_xor(32) pairs halves -> 8-time max.
        {
            const float s2f  = cst_s[32 + nlane];
            const float sh2f_unused = 0.0f; (void)sh2f_unused;

            union F8q { int4 q; f16x8 h; } af[7];
#pragma unroll
            for (int dt = 0; dt < 7; ++dt) {
                const int dwi = (dt * 256 + nlane * 8 + half * 4)
                                ^ (((nlane >> 2) & 3) << 3);
                af[dt].q = *(const int4*)((const int*)w2T_s + dwi);
            }

            for (int tile = wv; tile < 13; tile += 5) {
                const int tA  = tile * 32 + nlane;
                const int tAr = tA < 400 ? tA : 399;  // clamp; bad D rows are
                                                      // q>=2 -> pair>=50, discarded
                f32x16 acc;
#pragma unroll
                for (int i = 0; i < 16; ++i) acc[i] = 0.0f;

#pragma unroll
                for (int dt = 0; dt < 7; ++dt) {
                    const int* p = (const int*)y1T_s + (tAr + dt) * Y1T_STRIDE_I + half * 4;
                    union { int d[4]; f16x8 h; } bf;
                    bf.d[0] = p[0];
                    bf.d[1] = p[1];
                    bf.d[2] = p[2];
                    bf.d[3] = p[3];
                    acc = __builtin_amdgcn_mfma_f32_32x32x16_f16(bf.h, af[dt].h, acc, 0, 0, 0);
                }

#pragma unroll
                for (int q = 0; q < 4; ++q) {
                    // scale per element (sign-safe wrt g2), defer shift+relu
                    float v0 = acc[4 * q + 0] * s2f;
                    float v1 = acc[4 * q + 1] * s2f;
                    float v2 = acc[4 * q + 2] * s2f;
                    float v3 = acc[4 * q + 3] * s2f;
                    float m  = fmaxf(fmaxf(v0, v1), fmaxf(v2, v3));
                    float pm = fmaxf(m, __shfl_xor(m, 32));
                    const int pair = tile * 4 + q;
                    if (half == 0 && pair < 50)
                        segmax_s[nlane * SEG_STRIDE + pair] = (_Float16)pm;
                }
            }
        }
        __syncthreads();

        // ---- pool(40) = max of 5 pair-maxes; apply shift + relu ----
        {
            const int f = tid & 31;
            const int p = tid >> 5;
            float m = -3.0e38f;
#pragma unroll
            for (int k = 0; k < 5; ++k)
                m = fmaxf(m, (float)segmax_s[f * SEG_STRIDE + p * 5 + k]);
            float v = fmaxf(m + cst_s[64 + f], 0.0f);
            featH[(size_t)b * KFEAT + (c * 32 + f) * 10 + p] = (_Float16)v;
        }
        // barrier audit (R2-proven structure): next x-stage writes xs only
        // (last readers fenced by two syncs); segmax(i) fully consumed before
        // any wave passes the next post-stage sync; y1T rewritten only after
        // the post-stage sync.
    }
}

// ---------------------------------------------------------------------------
// FC1: 173 blocks x 512 threads (8 waves = 2/SIMD).
// Wave w: k-half kh=w>>2 (160 k, 10 steps), j-quarter jq=w&3. kh=1 tiles
// combined via LDS, then fp32 atomicAdd into h (prep zeroes h).
// ---------------------------------------------------------------------------
__global__ __launch_bounds__(512) void fc1_kernel(
    const _Float16* __restrict__ featH, const float* __restrict__ wc1,
    float* __restrict__ h_ws)
{
    __shared__ float red[4 * 2048];

    const int tid   = threadIdx.x;
    const int w     = tid >> 6;
    const int lane  = tid & 63;
    const int nlane = lane & 31;
    const int half  = lane >> 5;
    const int kh    = w >> 2;
    const int jq    = w & 3;
    const int jrow  = jq * 32 + nlane;
    const int k0    = blockIdx.x * 320 + kh * 160;

    const float*    ap  = wc1   + (size_t)jrow * KFEAT + k0 + half * 8;
    const _Float16* b0p = featH + (size_t)nlane * KFEAT + k0 + half * 8;
    const _Float16* b1p = featH + (size_t)(nlane + 32) * KFEAT + k0 + half * 8;

    f32x16 acc0, acc1;
#pragma unroll
    for (int i = 0; i < 16; ++i) { acc0[i] = 0.0f; acc1[i] = 0.0f; }

#pragma unroll 5
    for (int s = 0; s < 10; ++s) {
        const float4 aw0 = *(const float4*)(ap + s * 16);
        const float4 aw1 = *(const float4*)(ap + s * 16 + 4);
        union { fp16x2 v2[4]; f16x8 h; } a;
        a.v2[0] = __builtin_amdgcn_cvt_pkrtz(aw0.x, aw0.y);
        a.v2[1] = __builtin_amdgcn_cvt_pkrtz(aw0.z, aw0.w);
        a.v2[2] = __builtin_amdgcn_cvt_pkrtz(aw1.x, aw1.y);
        a.v2[3] = __builtin_amdgcn_cvt_pkrtz(aw1.z, aw1.w);

        union { int4 q; f16x8 h; } b0, b1;
        b0.q = *(const int4*)(b0p + s * 16);
        b1.q = *(const int4*)(b1p + s * 16);

        acc0 = __builtin_amdgcn_mfma_f32_32x32x16_f16(a.h, b0.h, acc0, 0, 0, 0);
        acc1 = __builtin_amdgcn_mfma_f32_32x32x16_f16(a.h, b1.h, acc1, 0, 0, 0);
    }

    if (kh == 1) {
        float* rp = red + jq * 2048;
#pragma unroll
        for (int reg = 0; reg < 16; ++reg) {
            rp[(reg * 2 + half) * 64 + nlane]      = acc0[reg];
            rp[(reg * 2 + half) * 64 + 32 + nlane] = acc1[reg];
        }
    }
    __syncthreads();
    if (kh == 0) {
        const float* rp = red + jq * 2048;
#pragma unroll
        for (int reg = 0; reg < 16; ++reg) {
            int j = jq * 32 + (reg & 3) + 8 * (reg >> 2) + 4 * half;
            float v0 = acc0[reg] + rp[(reg * 2 + half) * 64 + nlane];
            float v1 = acc1[reg] + rp[(reg * 2 + half) * 64 + 32 + nlane];
            atomicAdd(&h_ws[j * 64 + nlane], v0);
            atomicAdd(&h_ws[j * 64 + 32 + nlane], v1);
        }
    }
}

// ---------------------------------------------------------------------------
// FC2: one block, 512 threads. b = t&63 (coalesced h reads), j chunked 8-way.
// ---------------------------------------------------------------------------
__global__ __launch_bounds__(512) void fc2_kernel(
    const float* __restrict__ h_ws, const float* __restrict__ bc1,
    const float* __restrict__ wc2, const float* __restrict__ bc2,
    float* __restrict__ out)
{
    __shared__ float partial[512];
    const int t  = threadIdx.x;
    const int b  = t & 63;
    const int jc = t >> 6;
    float s = 0.0f;
#pragma unroll
    for (int jj = 0; jj < 16; ++jj) {
        const int j = jc * 16 + jj;
        float hv = h_ws[j * 64 + b] + bc1[j];
        hv = hv > 0.0f ? hv : 0.0f;
        s += wc2[j] * hv;
    }
    partial[t] = s;
    __syncthreads();
    if (t < 64) {
        float r = partial[t];
#pragma unroll
        for (int k = 1; k < 8; ++k) r += partial[t + 64 * k];
        out[b] = r + bc2[0];
    }
}

extern "C" void kernel_launch(void* const* d_in, const int* in_sizes, int n_in,
                              void* d_out, int out_size, void* d_ws, size_t ws_size,
                              hipStream_t stream)
{
    const float* x     = (const float*)d_in[0];
    const float* w1    = (const float*)d_in[1];
    const float* b1    = (const float*)d_in[2];
    const float* g1    = (const float*)d_in[3];
    const float* beta1 = (const float*)d_in[4];
    const float* m1    = (const float*)d_in[5];
    const float* v1    = (const float*)d_in[6];
    const float* w2    = (const float*)d_in[7];
    const float* b2    = (const float*)d_in[8];
    const float* g2    = (const float*)d_in[9];
    const float* beta2 = (const float*)d_in[10];
    const float* m2    = (const float*)d_in[11];
    const float* v2    = (const float*)d_in[12];
    const float* wc1   = (const float*)d_in[13];
    const float* bc1   = (const float*)d_in[14];
    const float* wc2   = (const float*)d_in[15];
    const float* bc2   = (const float*)d_in[16];

    char* ws = (char*)d_ws;
    _Float16* featH = (_Float16*)ws;                          // 7,086,080 B
    _Float16* w2T_g = (_Float16*)(ws + 7086080);              // 1,240,064 B
    _Float16* w1T_g = (_Float16*)(ws + 8326144);              // 177,152 B
    float*    sc_g  = (float*)(ws + 8503296);                 // 66,432 B
    float*    h_ws  = (float*)(ws + 8569728);                 // 32,768 B

    // (N1+N2+N3+NH) = 733,408 -> 2865 blocks of 256
    hipLaunchKernelGGL(prep_kernel, dim3(2865), dim3(256), 0, stream,
                       w1, b1, g1, beta1, m1, v1,
                       w2, b2, g2, beta2, m2, v2, w2T_g, w1T_g, sc_g, h_ws);

    hipLaunchKernelGGL(tower_kernel, dim3(C_CH, 16), dim3(320), 0, stream,
                       x, w2T_g, w1T_g, sc_g, featH);

    hipLaunchKernelGGL(fc1_kernel, dim3(173), dim3(512), 0, stream,
                       featH, wc1, h_ws);

    hipLaunchKernelGGL(fc2_kernel, dim3(1), dim3(512), 0, stream,
                       h_ws, bc1, wc2, bc2, (float*)d_out);
}

// Round 7
// 190.902 us; speedup vs baseline: 1.3903x; 1.0913x over previous
//
#include <hip/hip_runtime.h>

#define C_CH 173
#define L_IN 400
#define EPSV 1e-5f
#define KFEAT 55360  // C*32*10

typedef __fp16   fp16x2 __attribute__((ext_vector_type(2)));
typedef _Float16 f16x8  __attribute__((ext_vector_type(8)));
typedef float    f32x4  __attribute__((ext_vector_type(4)));
typedef float    f32x16 __attribute__((ext_vector_type(16)));

// y1T row: 16 f16 + 1 pad dword = 9 dwords (R2/R3-proven). Odd dword stride
// -> conv2 b32 reads and conv1 b32-pair writes conflict-free (gcd(9,32)=1).
#define Y1T_STRIDE_I 9
#define Y1T_ROWS   406  // row r = y1 time t+3; rows 0..2, 403..405 zeroed halo

// segmax: [f][sub], sub = 0..99. Stride 102 f16 = 51 dwords (R3-proven).
#define SEG_STRIDE 102

#define N1 (173 * 3584)  // w2T elems
#define N2 (173 * 512)   // w1T elems
#define N3 (173 * 96)    // BN consts per c
#define NH 8192          // h accumulator (zeroed in prep; fc1 atomicAdds)

// ---------------------------------------------------------------------------
// Prep kernel: per-channel weight layouts + BN consts + zero the h accum.
//  w2T_g[c][dt*512 + f*16 + g] f16 ; w1T_g[c][g*32+k] f16 (k>=9 zero)
//  sc_g[c*96 + r]: r<16 scale1 | r<32 shift1 | r<64 scale2 | r<96 shift2
// ---------------------------------------------------------------------------
__global__ __launch_bounds__(256) void prep_kernel(
    const float* __restrict__ w1, const float* __restrict__ b1,
    const float* __restrict__ g1, const float* __restrict__ beta1,
    const float* __restrict__ m1, const float* __restrict__ v1,
    const float* __restrict__ w2, const float* __restrict__ b2,
    const float* __restrict__ g2, const float* __restrict__ beta2,
    const float* __restrict__ m2, const float* __restrict__ v2,
    _Float16* __restrict__ w2T_g, _Float16* __restrict__ w1T_g,
    float* __restrict__ sc_g, float* __restrict__ h_ws)
{
    const int idx = blockIdx.x * 256 + threadIdx.x;
    if (idx < N1) {
        int c = idx / 3584, r = idx - c * 3584;
        int dt = r >> 9, fg = r & 511;
        int f = fg >> 4, g = fg & 15;
        w2T_g[idx] = (_Float16)w2[c * 3584 + f * 112 + g * 7 + dt];
    } else if (idx < N1 + N2) {
        int j = idx - N1;
        int c = j / 512, r = j - c * 512;
        int g = r >> 5, k = r & 31;
        w1T_g[j] = (k < 9) ? (_Float16)w1[c * 144 + g * 9 + k] : (_Float16)0.0f;
    } else if (idx < N1 + N2 + N3) {
        int j = idx - N1 - N2;
        int c = j / 96, r = j - c * 96;
        float o;
        if (r < 32) {
            int g  = r & 15;
            int cf = c * 16 + g;
            float inv = g1[cf] * rsqrtf(v1[cf] + EPSV);
            o = (r < 16) ? inv : (b1[cf] - m1[cf]) * inv + beta1[cf];
        } else {
            int f  = (r - 32) & 31;
            int cf = c * 32 + f;
            float inv = g2[cf] * rsqrtf(v2[cf] + EPSV);
            o = (r < 64) ? inv : (b2[cf] - m2[cf]) * inv + beta2[cf];
        }
        sc_g[j] = o;
    } else if (idx < N1 + N2 + N3 + NH) {
        h_ws[idx - N1 - N2 - N3] = 0.0f;
    }
}

// ---------------------------------------------------------------------------
// Tower kernel: EXACT R3 configuration (measured 70.8-73.1 us, best known).
// One block per (c, batch-group of 4). 320 threads = 5 waves.
// conv2: A=y1 (time rows), B=w2 (f lanes) -> per-lane register pool max.
// af[7] hoisted to block scope (R3: -1.16M conflicts vs per-batch).
// NO shfl pair-combine, NO xs merge, NO w2T swizzle (R6 showed the swizzle
// is a provable no-op — XOR permutes lanes, not the start-bank histogram —
// and the trio cost +14us vs this structure).
// ---------------------------------------------------------------------------
__global__ __launch_bounds__(320, 7) void tower_kernel(
    const float* __restrict__ x,
    const _Float16* __restrict__ w2T_g, const _Float16* __restrict__ w1T_g,
    const float* __restrict__ sc_g,
    _Float16* __restrict__ featH)
{
    __shared__ __align__(16) _Float16 xa_s[432];             // xa[i] = x_s[i]
    __shared__ __align__(16) _Float16 xb_s[432];             // xb[i] = x_s[i+1]
    __shared__ __align__(16) _Float16 w1T_s[16 * 32];        // [g][k]
    __shared__ __align__(16) _Float16 y1T_s[Y1T_ROWS * 2 * Y1T_STRIDE_I];
    __shared__ __align__(16) _Float16 w2T_s[7 * 512];        // [dt][f][g]
    __shared__ _Float16               segmax_s[32 * SEG_STRIDE]; // [f][sub]
    __shared__ __align__(16) float    cst_s[96];  // s1[16] sh1[16] s2[32] sh2[32]

    const int c   = blockIdx.x;
    const int tid = threadIdx.x;

    // ---- once-per-block staging (coalesced, no div/cvt/scatter) ----
    {
        const int4* w2src = (const int4*)(w2T_g + (size_t)c * 3584);
        for (int i = tid; i < 448; i += 320) ((int4*)w2T_s)[i] = w2src[i];
        const int4* w1src = (const int4*)(w1T_g + c * 512);
        if (tid < 64) ((int4*)w1T_s)[tid] = w1src[tid];
        const float4* csrc = (const float4*)(sc_g + c * 96);
        if (tid >= 64 && tid < 88) ((float4*)cst_s)[tid - 64] = csrc[tid - 64];
        // zero y1T halo rows 0..2 and 403..405 (6 rows x 9 dwords)
        if (tid >= 88 && tid < 142) {
            int i = tid - 88;
            int r = i / 9, cx = i - r * 9;
            int row = (r < 3) ? r : (400 + r);
            ((int*)y1T_s)[row * Y1T_STRIDE_I + cx] = 0;
        }
    }
    __syncthreads();
    // per-lane BN consts for conv2/pool (f = tid&31 in both scopes)
    const float s2f  = cst_s[32 + (tid & 31)];
    const float sh2f = cst_s[64 + (tid & 31)];

    // ---- hoisted conv2 weight fragments (loop-invariant across batches) ----
    const int nlaneH = tid & 31;
    const int halfH  = (tid >> 5) & 1;
    union F8q { int4 q; f16x8 h; } af[7];
#pragma unroll
    for (int dt = 0; dt < 7; ++dt)
        af[dt].q = *(const int4*)((const int*)w2T_s + dt * 256 + nlaneH * 8 + halfH * 4);

    for (int nb = 0; nb < 4; ++nb) {
        const int b = blockIdx.y * 4 + nb;

        // ---- stage x as f16 parity copies ----
        const float* xrow = x + ((size_t)b * C_CH + c) * L_IN;
        for (int i = tid; i < 432; i += 320) {
            float v = (i >= 4 && i < 404) ? xrow[i - 4] : 0.0f;
            _Float16 h = (_Float16)v;
            xa_s[i] = h;
            if (i > 0) xb_s[i - 1] = h;
        }
        if (tid == 0) xb_s[431] = (_Float16)0.0f;
        __syncthreads();

        // ---- conv1 via mfma_16x16x32_f16 -> y1T ----
        // A[m=g][k]=w1T; B[k][n]=x_s[t0+n+k-4] (+4 shift folded into x_s).
        {
            const int lane = tid & 63;
            const int wv5  = tid >> 6;
            const int nl   = lane & 15;
            const int q    = lane >> 4;
            union { int4 v; f16x8 h; } a1;
            a1.v = *(const int4*)((const int*)w1T_s + nl * 16 + q * 4);
            float s1r[4], sh1r[4];
#pragma unroll
            for (int r = 0; r < 4; ++r) {
                s1r[r]  = cst_s[q * 4 + r];
                sh1r[r] = cst_s[16 + q * 4 + r];
            }
            const int* xsel = (const int*)((nl & 1) ? xb_s : xa_s);
            for (int tile = 0; tile < 5; ++tile) {
                const int t0 = (wv5 * 5 + tile) * 16;
                const int dw = (t0 + nl + q * 8) >> 1;
                union { int4 v; f16x8 h; } bf;
                bf.v.x = xsel[dw];
                bf.v.y = xsel[dw + 1];
                bf.v.z = xsel[dw + 2];
                bf.v.w = xsel[dw + 3];
                f32x4 acc = {0.0f, 0.0f, 0.0f, 0.0f};
                acc = __builtin_amdgcn_mfma_f32_16x16x32_f16(a1.h, bf.h, acc, 0, 0, 0);
                union { _Float16 h[4]; int2 d; } pk;
#pragma unroll
                for (int r = 0; r < 4; ++r) {
                    float v = acc[r] * s1r[r] + sh1r[r];
                    pk.h[r] = (_Float16)(v > 0.0f ? v : 0.0f);
                }
                // stride-9 rows are only 4B aligned: two b32 stores
                int* yp = (int*)y1T_s + (t0 + nl + 3) * Y1T_STRIDE_I + q * 2;
                yp[0] = pk.d.x;
                yp[1] = pk.d.y;
            }
        }
        __syncthreads();

        // ---- conv2 MFMA (swapped operands) + scaled per-lane subseg max ----
        // acc = D[t][f]: f = lane&31, t = t0 + (reg&3) + 8*(reg>>2) + 4*half.
        // Subseg (4 times) = one reg quad; sub = tile*8 + 2q + half.
        {
            const int wv    = tid >> 6;
            const int nlane = nlaneH;
            const int half  = halfH;

            for (int tile = wv; tile < 13; tile += 5) {
                const int tA  = tile * 32 + nlane;        // A-row time (lane)
                const int tAr = tA < 400 ? tA : 399;      // clamp; bad rows -> discarded regs
                f32x16 acc;
#pragma unroll
                for (int i = 0; i < 16; ++i) acc[i] = 0.0f;

#pragma unroll
                for (int dt = 0; dt < 7; ++dt) {
                    const int* p = (const int*)y1T_s + (tAr + dt) * Y1T_STRIDE_I + half * 4;
                    union { int d[4]; f16x8 h; } bf;
                    bf.d[0] = p[0];
                    bf.d[1] = p[1];
                    bf.d[2] = p[2];
                    bf.d[3] = p[3];
                    acc = __builtin_amdgcn_mfma_f32_32x32x16_f16(bf.h, af[dt].h, acc, 0, 0, 0);
                }

                const int base = nlane * SEG_STRIDE + tile * 8 + half;
#pragma unroll
                for (int q = 0; q < 4; ++q) {
                    // scale per element (sign-safe wrt g2), defer shift+relu
                    float v0 = acc[4 * q + 0] * s2f;
                    float v1 = acc[4 * q + 1] * s2f;
                    float v2 = acc[4 * q + 2] * s2f;
                    float v3 = acc[4 * q + 3] * s2f;
                    float m  = fmaxf(fmaxf(v0, v1), fmaxf(v2, v3));
                    const int sub = tile * 8 + 2 * q + half;
                    if (sub < 100) segmax_s[base + 2 * q] = (_Float16)m;
                }
            }
        }
        __syncthreads();

        // ---- pool(40) = max of 10 subseg-maxes; apply shift + relu ----
        {
            const int f = tid & 31;
            const int p = tid >> 5;
            float m = -3.0e38f;
#pragma unroll
            for (int k = 0; k < 10; ++k)
                m = fmaxf(m, (float)segmax_s[f * SEG_STRIDE + p * 10 + k]);
            float v = fmaxf(m + sh2f, 0.0f);
            featH[(size_t)b * KFEAT + (c * 32 + f) * 10 + p] = (_Float16)v;
        }
        // no trailing sync needed: next iter's x-stage touches xa/xb only;
        // segmax(i) is fully consumed before any wave passes the next
        // post-stage sync; y1T rewritten only after the post-stage sync.
    }
}

// ---------------------------------------------------------------------------
// FC1: grid (173, 2) x 512 threads — R7: batch-split. Each block computes a
// 128(j) x 32(b) tile for one c-slice of K (320). 346 blocks (was 173) —
// fc1 was occupancy/latency-bound at 0.68 blocks/CU with 1/3 of the GPU
// idle. wc1 re-read (+28MB) is L3-resident (wc1 = 28MB < 256MB L3).
// Wave w: k-half kh=w>>2 (160 k, 10 steps), j-quarter jq=w&3. kh=1 tiles
// combined via LDS, then fp32 atomicAdd into h (prep zeroes h; atomic count
// unchanged: each h element still gets exactly 173 adds).
// ---------------------------------------------------------------------------
__global__ __launch_bounds__(512) void fc1_kernel(
    const _Float16* __restrict__ featH, const float* __restrict__ wc1,
    float* __restrict__ h_ws)
{
    __shared__ float red[4 * 1024];

    const int tid   = threadIdx.x;
    const int w     = tid >> 6;
    const int lane  = tid & 63;
    const int nlane = lane & 31;
    const int half  = lane >> 5;
    const int kh    = w >> 2;
    const int jq    = w & 3;
    const int jrow  = jq * 32 + nlane;
    const int bh    = blockIdx.y;
    const int k0    = blockIdx.x * 320 + kh * 160;

    const float*    ap  = wc1   + (size_t)jrow * KFEAT + k0 + half * 8;
    const _Float16* b0p = featH + (size_t)(bh * 32 + nlane) * KFEAT + k0 + half * 8;

    f32x16 acc0;
#pragma unroll
    for (int i = 0; i < 16; ++i) acc0[i] = 0.0f;

#pragma unroll 5
    for (int s = 0; s < 10; ++s) {
        const float4 aw0 = *(const float4*)(ap + s * 16);
        const float4 aw1 = *(const float4*)(ap + s * 16 + 4);
        union { fp16x2 v2[4]; f16x8 h; } a;
        a.v2[0] = __builtin_amdgcn_cvt_pkrtz(aw0.x, aw0.y);
        a.v2[1] = __builtin_amdgcn_cvt_pkrtz(aw0.z, aw0.w);
        a.v2[2] = __builtin_amdgcn_cvt_pkrtz(aw1.x, aw1.y);
        a.v2[3] = __builtin_amdgcn_cvt_pkrtz(aw1.z, aw1.w);

        union { int4 q; f16x8 h; } b0;
        b0.q = *(const int4*)(b0p + s * 16);

        acc0 = __builtin_amdgcn_mfma_f32_32x32x16_f16(a.h, b0.h, acc0, 0, 0, 0);
    }

    if (kh == 1) {
        float* rp = red + jq * 1024;
#pragma unroll
        for (int reg = 0; reg < 16; ++reg)
            rp[(reg * 2 + half) * 32 + nlane] = acc0[reg];
    }
    __syncthreads();
    if (kh == 0) {
        const float* rp = red + jq * 1024;
#pragma unroll
        for (int reg = 0; reg < 16; ++reg) {
            int j = jq * 32 + (reg & 3) + 8 * (reg >> 2) + 4 * half;
            float v0 = acc0[reg] + rp[(reg * 2 + half) * 32 + nlane];
            atomicAdd(&h_ws[j * 64 + bh * 32 + nlane], v0);
        }
    }
}

// ---------------------------------------------------------------------------
// FC2: one block, 512 threads. b = t&63 (coalesced h reads), j chunked 8-way.
// ---------------------------------------------------------------------------
__global__ __launch_bounds__(512) void fc2_kernel(
    const float* __restrict__ h_ws, const float* __restrict__ bc1,
    const float* __restrict__ wc2, const float* __restrict__ bc2,
    float* __restrict__ out)
{
    __shared__ float partial[512];
    const int t  = threadIdx.x;
    const int b  = t & 63;
    const int jc = t >> 6;
    float s = 0.0f;
#pragma unroll
    for (int jj = 0; jj < 16; ++jj) {
        const int j = jc * 16 + jj;
        float hv = h_ws[j * 64 + b] + bc1[j];
        hv = hv > 0.0f ? hv : 0.0f;
        s += wc2[j] * hv;
    }
    partial[t] = s;
    __syncthreads();
    if (t < 64) {
        float r = partial[t];
#pragma unroll
        for (int k = 1; k < 8; ++k) r += partial[t + 64 * k];
        out[b] = r + bc2[0];
    }
}

extern "C" void kernel_launch(void* const* d_in, const int* in_sizes, int n_in,
                              void* d_out, int out_size, void* d_ws, size_t ws_size,
                              hipStream_t stream)
{
    const float* x     = (const float*)d_in[0];
    const float* w1    = (const float*)d_in[1];
    const float* b1    = (const float*)d_in[2];
    const float* g1    = (const float*)d_in[3];
    const float* beta1 = (const float*)d_in[4];
    const float* m1    = (const float*)d_in[5];
    const float* v1    = (const float*)d_in[6];
    const float* w2    = (const float*)d_in[7];
    const float* b2    = (const float*)d_in[8];
    const float* g2    = (const float*)d_in[9];
    const float* beta2 = (const float*)d_in[10];
    const float* m2    = (const float*)d_in[11];
    const float* v2    = (const float*)d_in[12];
    const float* wc1   = (const float*)d_in[13];
    const float* bc1   = (const float*)d_in[14];
    const float* wc2   = (const float*)d_in[15];
    const float* bc2   = (const float*)d_in[16];

    char* ws = (char*)d_ws;
    _Float16* featH = (_Float16*)ws;                          // 7,086,080 B
    _Float16* w2T_g = (_Float16*)(ws + 7086080);              // 1,240,064 B
    _Float16* w1T_g = (_Float16*)(ws + 8326144);              // 177,152 B
    float*    sc_g  = (float*)(ws + 8503296);                 // 66,432 B
    float*    h_ws  = (float*)(ws + 8569728);                 // 32,768 B

    // (N1+N2+N3+NH) = 733,408 -> 2865 blocks of 256
    hipLaunchKernelGGL(prep_kernel, dim3(2865), dim3(256), 0, stream,
                       w1, b1, g1, beta1, m1, v1,
                       w2, b2, g2, beta2, m2, v2, w2T_g, w1T_g, sc_g, h_ws);

    hipLaunchKernelGGL(tower_kernel, dim3(C_CH, 16), dim3(320), 0, stream,
                       x, w2T_g, w1T_g, sc_g, featH);

    hipLaunchKernelGGL(fc1_kernel, dim3(173, 2), dim3(512), 0, stream,
                       featH, wc1, h_ws);

    hipLaunchKernelGGL(fc2_kernel, dim3(1), dim3(512), 0, stream,
                       h_ws, bc1, wc2, bc2, (float*)d_out);
}